// Round 17
// baseline (845.202 us; speedup 1.0000x reference)
//
#include <hip/hip_runtime.h>
#include <hip/hip_bf16.h>
#include <stdint.h>

#define TT   8192   // B*S tokens
#define DD   2048
#define MM   2048
#define NE   8

typedef float f32x4 __attribute__((ext_vector_type(4)));
typedef short s16x8 __attribute__((ext_vector_type(8)));
typedef unsigned int u32;
typedef unsigned long long u64;

static __device__ __forceinline__ short f2bf(float f) {
  __hip_bfloat16 h = __float2bfloat16(f);
  short s;
  __builtin_memcpy(&s, &h, 2);
  return s;
}
static __device__ __forceinline__ float bf2f(short s) {
  u32 u = ((u32)(unsigned short)s) << 16;
  float f;
  __builtin_memcpy(&f, &u, 4);
  return f;
}

static __device__ __forceinline__ void gload_lds16(const short* g, short* lds) {
  __builtin_amdgcn_global_load_lds(
      (const __attribute__((address_space(1))) u32*)g,
      (__attribute__((address_space(3))) u32*)lds, 16, 0, 0);
}

// ================= FUSED: gate+xcvt (blocks 0..TT) + wi0/wi1 transpose (rest) =========
#define GCVT01  (16 * 32 * 32)     // 16384 transpose tiles (wi0, wi1)

__global__ __launch_bounds__(256) void gate_fused(
    const float* __restrict__ x, const float* __restrict__ gk,
    int* __restrict__ counts, int* __restrict__ tkidx, float* __restrict__ tkw,
    short* __restrict__ xbf,
    const float* __restrict__ wi0, const float* __restrict__ wi1,
    short* __restrict__ o0, short* __restrict__ o1) {
  __shared__ short tile[64][65];
  __shared__ float red[4][NE];

  const int bid = blockIdx.x;
  if (bid >= TT) {
    // ---- tcvt01 role: transpose-convert one 64x64 tile of wi0/wi1 ----
    const int idx = bid - TT;
    const int wz = idx >> 10;                // 0..15
    const float* in  = (wz < 8) ? wi0 : wi1;
    short* out       = (wz < 8) ? o0 : o1;
    const int ex = wz & 7;
    const int rem = idx & 1023;
    const int r0 = (rem >> 5) * 64;
    const int c0 = (rem & 31) * 64;
    const float* src = in + (size_t)ex * DD * MM;
    short* dst = out + (size_t)ex * DD * MM;
    const int t = threadIdx.x;
    const int rr = t >> 4, cc = (t & 15) * 4;
    #pragma unroll
    for (int i = 0; i < 4; i++) {
      int row = rr + i * 16;
      f32x4 v = *(const f32x4*)(src + (size_t)(r0 + row) * MM + c0 + cc);
      tile[cc + 0][row] = f2bf(v[0]);
      tile[cc + 1][row] = f2bf(v[1]);
      tile[cc + 2][row] = f2bf(v[2]);
      tile[cc + 3][row] = f2bf(v[3]);
    }
    __syncthreads();
    const int orow = t >> 2, c8 = (t & 3) * 16;
    s16x8 v0, v1;
    #pragma unroll
    for (int i = 0; i < 8; i++) { v0[i] = tile[orow][c8 + i]; v1[i] = tile[orow][c8 + 8 + i]; }
    short* dp = dst + (size_t)(c0 + orow) * DD + r0 + c8;
    *(s16x8*)(dp) = v0;
    *(s16x8*)(dp + 8) = v1;
    return;
  }

  // ---- gate role: fp32 logits, top-2, softmax; writes xbf ----
  const int t = bid;
  const float* xr = x + (size_t)t * DD;
  const int d0 = threadIdx.x * 8;
  f32x4 a = *(const f32x4*)(xr + d0);
  f32x4 b = *(const f32x4*)(xr + d0 + 4);
  s16x8 v;
  v[0]=f2bf(a[0]); v[1]=f2bf(a[1]); v[2]=f2bf(a[2]); v[3]=f2bf(a[3]);
  v[4]=f2bf(b[0]); v[5]=f2bf(b[1]); v[6]=f2bf(b[2]); v[7]=f2bf(b[3]);
  *(s16x8*)(xbf + (size_t)t * DD + d0) = v;

  float acc[NE];
  #pragma unroll
  for (int e = 0; e < NE; e++) acc[e] = 0.f;
  #pragma unroll
  for (int j = 0; j < 8; j++) {
    float xv = (j < 4) ? a[j] : b[j - 4];
    const float* g = gk + (size_t)(d0 + j) * NE;
    #pragma unroll
    for (int e = 0; e < NE; e++) acc[e] += xv * g[e];
  }
  #pragma unroll
  for (int e = 0; e < NE; e++) {
    #pragma unroll
    for (int off = 32; off >= 1; off >>= 1)
      acc[e] += __shfl_xor(acc[e], off, 64);
  }
  int wid = threadIdx.x >> 6;
  int lane = threadIdx.x & 63;
  if (lane == 0) {
    #pragma unroll
    for (int e = 0; e < NE; e++) red[wid][e] = acc[e];
  }
  __syncthreads();
  if (threadIdx.x == 0) {
    float l[NE];
    #pragma unroll
    for (int e = 0; e < NE; e++) l[e] = red[0][e] + red[1][e] + red[2][e] + red[3][e];
    int i1 = 0; float v1 = l[0];
    #pragma unroll
    for (int e = 1; e < NE; e++) if (l[e] > v1) { v1 = l[e]; i1 = e; }
    int i2 = -1; float v2 = -1e30f;
    #pragma unroll
    for (int e = 0; e < NE; e++) if (e != i1 && l[e] > v2) { v2 = l[e]; i2 = e; }
    float p = __expf(v2 - v1);
    float inv = 1.f / (1.f + p);
    tkidx[t*2]   = i1; tkidx[t*2+1] = i2;
    tkw[t*2]     = inv; tkw[t*2+1]  = p * inv;
    atomicAdd(&counts[i1], 1);
    atomicAdd(&counts[i2], 1);
  }
}

// ---------------- scatter: 8 blocks, deterministic ballot compaction (+ slot map) ------
__global__ __launch_bounds__(256) void scatter_kernel(const int* __restrict__ counts,
    int* __restrict__ offsets, const int* __restrict__ tkidx,
    const float* __restrict__ tkw, int* __restrict__ ltok, float* __restrict__ lwt,
    int* __restrict__ slots) {
  const int e = blockIdx.x;
  const int tid = threadIdx.x;
  const int wid = tid >> 6, lane = tid & 63;
  __shared__ int base_s;
  __shared__ int wsum[4];
  if (tid == 0) {
    int s = 0;
    #pragma unroll
    for (int i = 0; i < NE; i++) {
      if (e == 0) offsets[i] = s;
      if (i < e) s += counts[i];
      else if (e == 0) s += counts[i];
    }
    if (e == 0) offsets[NE] = s;
    int bs = 0;
    for (int i = 0; i < e; i++) bs += counts[i];
    base_s = bs;
  }
  __syncthreads();
  int base = base_s;
  for (int it = 0; it < (TT * 2) / 256; it++) {
    int i = it * 256 + tid;
    bool m = (tkidx[i] == e);
    u64 b = __ballot(m);
    if (lane == 0) wsum[wid] = __popcll(b);
    __syncthreads();
    int pre = 0;
    #pragma unroll
    for (int w = 0; w < 4; w++) if (w < wid) pre += wsum[w];
    int tot = wsum[0] + wsum[1] + wsum[2] + wsum[3];
    int rank = __popcll(b & ((lane == 0) ? 0ull : ((1ull << lane) - 1ull)));
    if (m) {
      int dst = base + pre + rank;
      ltok[dst] = i >> 1;
      lwt[dst]  = tkw[i];
      slots[i]  = dst;
    }
    __syncthreads();
    base += tot;
  }
}

// ---------------- combine: out[t] = sum of 4 bf16 partial rows ----------------
__global__ __launch_bounds__(256) void combine_kernel(const short* __restrict__ c0,
    const short* __restrict__ c1, const int* __restrict__ slots,
    float* __restrict__ out) {
  const int t = blockIdx.x;
  const int s0 = slots[2 * t], s1 = slots[2 * t + 1];
  const int idx = threadIdx.x;
  s16x8 a0 = *(const s16x8*)(c0 + (size_t)s0 * DD + idx * 8);
  s16x8 a1 = *(const s16x8*)(c1 + (size_t)s0 * DD + idx * 8);
  s16x8 b0 = *(const s16x8*)(c0 + (size_t)s1 * DD + idx * 8);
  s16x8 b1 = *(const s16x8*)(c1 + (size_t)s1 * DD + idx * 8);
  f32x4 o0, o1;
  #pragma unroll
  for (int j = 0; j < 4; j++) {
    o0[j] = (bf2f(a0[j]) + bf2f(a1[j])) + (bf2f(b0[j]) + bf2f(b1[j]));
    o1[j] = (bf2f(a0[4+j]) + bf2f(a1[4+j])) + (bf2f(b0[4+j]) + bf2f(b1[4+j]));
  }
  float* po = out + (size_t)t * DD + idx * 8;
  *(f32x4*)(po) = o0;
  *(f32x4*)(po + 4) = o1;
}

// ---------------- segment lookup ----------------
__device__ __forceinline__ void find_seg(const int* __restrict__ offsets, int tile, int bm,
                                         int& e, int& row0, int& rows, int& seg) {
  e = -1; row0 = 0; rows = 0; seg = 0;
  int accT = 0, prev = offsets[0];
  #pragma unroll
  for (int i = 0; i < NE; i++) {
    int nxt = offsets[i+1];
    int cnt = nxt - prev;
    int nt = (cnt + bm - 1) / bm;
    if (e < 0 && tile < accT + nt) { e = i; row0 = (tile - accT) * bm; rows = cnt; seg = prev; }
    accT += nt; prev = nxt;
  }
}

// ================= FUSED: gemm1 (blocks 0..G1GRID) + wo-transpose (rest) =================
#define G1TILES 136
#define G1GRID  (G1TILES * 16)     // 2176, %8==0 (bijective swizzle)
#define GOGRID  (8 * 32 * 32)      // 8192 transpose tiles

__global__ __launch_bounds__(256, 2) void gemm1_fused(
    const short* __restrict__ xbf,
    const short* __restrict__ w0t, const short* __restrict__ w1t,
    const int* __restrict__ offsets,
    const int* __restrict__ ltok, const float* __restrict__ lwt,
    short* __restrict__ hbuf,
    const float* __restrict__ wo, short* __restrict__ wot) {
  __shared__ short As[128 * 64];
  __shared__ short B0s[128 * 64];
  __shared__ short B1s[128 * 64];
  __shared__ float w_s[128];

  const int bid = blockIdx.x;
  if (bid >= G1GRID) {
    short (*tile)[65] = (short(*)[65])As;
    const int idx = bid - G1GRID;
    const int ex = idx >> 10;
    const int rem = idx & 1023;
    const int r0 = (rem >> 5) * 64;
    const int c0 = (rem & 31) * 64;
    const float* src = wo + (size_t)ex * DD * MM;
    short* dst = wot + (size_t)ex * DD * MM;
    const int t = threadIdx.x;
    const int rr = t >> 4, cc = (t & 15) * 4;
    #pragma unroll
    for (int i = 0; i < 4; i++) {
      int row = rr + i * 16;
      f32x4 v = *(const f32x4*)(src + (size_t)(r0 + row) * MM + c0 + cc);
      tile[cc + 0][row] = f2bf(v[0]);
      tile[cc + 1][row] = f2bf(v[1]);
      tile[cc + 2][row] = f2bf(v[2]);
      tile[cc + 3][row] = f2bf(v[3]);
    }
    __syncthreads();
    const int orow = t >> 2, c8 = (t & 3) * 16;
    s16x8 v0, v1;
    #pragma unroll
    for (int i = 0; i < 8; i++) { v0[i] = tile[orow][c8 + i]; v1[i] = tile[orow][c8 + 8 + i]; }
    short* dp = dst + (size_t)(c0 + orow) * DD + r0 + c8;
    *(s16x8*)(dp) = v0;
    *(s16x8*)(dp + 8) = v1;
    return;
  }

  const int xcd = bid & 7;
  const int bi = bid >> 3;
  const int tile = bi >> 1;
  const int nyi = xcd * 2 + (bi & 1);
  const int n0 = nyi * 128;
  int e, row0, rows, seg;
  find_seg(offsets, tile, 128, e, row0, rows, seg);
  if (e < 0) return;

  const int tid = threadIdx.x;
  const int lane = tid & 63, wid = tid >> 6;
  if (tid < 128) {
    int gr = row0 + tid;
    w_s[tid] = (gr < rows) ? lwt[seg + gr] : 0.f;
  }

  const int swz = ((lane & 7) ^ (lane >> 3)) * 8;
  const short* abase[4];
  const short* b0base[4];
  const short* b1base[4];
  #pragma unroll
  for (int c = 0; c < 4; c++) {
    int chunk = wid * 4 + c;
    int r = chunk * 8 + (lane >> 3);
    int gr = row0 + r; if (gr >= rows) gr = rows - 1;
    int tok = ltok[seg + gr];
    abase[c]  = xbf + (size_t)tok * DD + swz;
    int n = n0 + r;
    b0base[c] = w0t + ((size_t)e * MM + n) * DD + swz;
    b1base[c] = w1t + ((size_t)e * MM + n) * DD + swz;
  }

  const int wr = wid >> 1, wc = wid & 1;
  const int lr = lane & 15;
  const int kq = (lane >> 4) * 8;

  f32x4 acc0[4][4], acc1[4][4];
  #pragma unroll
  for (int i = 0; i < 4; i++)
    #pragma unroll
    for (int j = 0; j < 4; j++) { acc0[i][j] = 0.f; acc1[i][j] = 0.f; }

  for (int k0 = 0; k0 < DD; k0 += 64) {
    #pragma unroll
    for (int c = 0; c < 4; c++) {
      int chunk = wid * 4 + c;
      gload_lds16(abase[c]  + k0, As  + chunk * 512);
      gload_lds16(b0base[c] + k0, B0s + chunk * 512);
      gload_lds16(b1base[c] + k0, B1s + chunk * 512);
    }
    __syncthreads();

    #pragma unroll
    for (int ks = 0; ks < 2; ks++) {
      s16x8 a[4], b0[4], b1[4];
      #pragma unroll
      for (int mi = 0; mi < 4; mi++) {
        int row = wr * 64 + mi * 16 + lr;
        int koff = (ks * 32 + kq) ^ ((row & 7) * 8);
        a[mi] = *(const s16x8*)&As[row * 64 + koff];
      }
      #pragma unroll
      for (int ni = 0; ni < 4; ni++) {
        int row = wc * 64 + ni * 16 + lr;
        int koff = (ks * 32 + kq) ^ ((row & 7) * 8);
        b0[ni] = *(const s16x8*)&B0s[row * 64 + koff];
        b1[ni] = *(const s16x8*)&B1s[row * 64 + koff];
      }
      #pragma unroll
      for (int mi = 0; mi < 4; mi++)
        #pragma unroll
        for (int ni = 0; ni < 4; ni++) {
          acc0[mi][ni] = __builtin_amdgcn_mfma_f32_16x16x32_bf16(a[mi], b0[ni], acc0[mi][ni], 0, 0, 0);
          acc1[mi][ni] = __builtin_amdgcn_mfma_f32_16x16x32_bf16(a[mi], b1[ni], acc1[mi][ni], 0, 0, 0);
        }
    }
    __syncthreads();
  }

  const int lq = lane >> 4;
  #pragma unroll
  for (int mi = 0; mi < 4; mi++) {
    #pragma unroll
    for (int jj = 0; jj < 4; jj++) {
      int r = wr * 64 + mi * 16 + lq * 4 + jj;
      int gr = row0 + r;
      if (gr < rows) {
        float wgt = w_s[r];
        size_t hrow = (size_t)(seg + gr) * MM + n0;
        #pragma unroll
        for (int ni = 0; ni < 4; ni++) {
          int c = wc * 64 + ni * 16 + lr;
          float g = acc0[mi][ni][jj];
          float u = acc1[mi][ni][jj];
          float act = g / (1.f + __expf(-g));
          hbuf[hrow + c] = f2bf(act * u * wgt);
        }
      }
    }
  }
}

// ================= GEMM2: 2-barrier, BM=128 x dual-B BN=256, K-split (2 halves) ======
// grid (136, 16): y<8 -> K-half 0 -> comb0; y>=8 -> K-half 1 -> comb1.
__global__ __launch_bounds__(256, 2) void gemm2_fast(
    const short* __restrict__ hbuf,
    const short* __restrict__ wot,
    const int* __restrict__ offsets,
    short* __restrict__ comb0, short* __restrict__ comb1) {
  __shared__ short As[128 * 64];
  __shared__ short B0s[128 * 64];
  __shared__ short B1s[128 * 64];

  // decode: 2176 blocks, %8==0 bijective. xcd gets {tile, kh} pairs; nyi = xcd.
  const int bid = blockIdx.y * gridDim.x + blockIdx.x;
  const int xcd = bid & 7;
  const int i = bid >> 3;            // [0, 272)
  const int kh = i & 1;
  const int tile = i >> 1;           // [0, 136)
  const int nyi = xcd;
  const int n0 = nyi * 256;
  const int kbase = kh * (MM / 2);
  int e, row0, rows, seg;
  find_seg(offsets, tile, 128, e, row0, rows, seg);
  if (e < 0) return;

  const int tid = threadIdx.x;
  const int lane = tid & 63, wid = tid >> 6;

  const int swz = ((lane & 7) ^ (lane >> 3)) * 8;
  const short* abase[4];
  const short* b0base[4];
  const short* b1base[4];
  #pragma unroll
  for (int c = 0; c < 4; c++) {
    int chunk = wid * 4 + c;
    int r = chunk * 8 + (lane >> 3);
    int gr = row0 + r; if (gr >= rows) gr = rows - 1;
    abase[c] = hbuf + (size_t)(seg + gr) * MM + kbase + swz;
    b0base[c] = wot + ((size_t)e * DD + n0 + r) * MM + kbase + swz;
    b1base[c] = wot + ((size_t)e * DD + n0 + 128 + r) * MM + kbase + swz;
  }

  const int wr = wid >> 1, wc = wid & 1;
  const int lr = lane & 15;
  const int kq = (lane >> 4) * 8;

  f32x4 acc0[4][4], acc1[4][4];
  #pragma unroll
  for (int i2 = 0; i2 < 4; i2++)
    #pragma unroll
    for (int j = 0; j < 4; j++) { acc0[i2][j] = 0.f; acc1[i2][j] = 0.f; }

  for (int k0 = 0; k0 < MM / 2; k0 += 64) {
    #pragma unroll
    for (int c = 0; c < 4; c++) {
      int chunk = wid * 4 + c;
      gload_lds16(abase[c]  + k0, As  + chunk * 512);
      gload_lds16(b0base[c] + k0, B0s + chunk * 512);
      gload_lds16(b1base[c] + k0, B1s + chunk * 512);
    }
    __syncthreads();

    #pragma unroll
    for (int ks = 0; ks < 2; ks++) {
      s16x8 a[4], b0[4], b1[4];
      #pragma unroll
      for (int mi = 0; mi < 4; mi++) {
        int row = wr * 64 + mi * 16 + lr;
        int koff = (ks * 32 + kq) ^ ((row & 7) * 8);
        a[mi] = *(const s16x8*)&As[row * 64 + koff];
      }
      #pragma unroll
      for (int ni = 0; ni < 4; ni++) {
        int row = wc * 64 + ni * 16 + lr;
        int koff = (ks * 32 + kq) ^ ((row & 7) * 8);
        b0[ni] = *(const s16x8*)&B0s[row * 64 + koff];
        b1[ni] = *(const s16x8*)&B1s[row * 64 + koff];
      }
      #pragma unroll
      for (int mi = 0; mi < 4; mi++)
        #pragma unroll
        for (int ni = 0; ni < 4; ni++) {
          acc0[mi][ni] = __builtin_amdgcn_mfma_f32_16x16x32_bf16(a[mi], b0[ni], acc0[mi][ni], 0, 0, 0);
          acc1[mi][ni] = __builtin_amdgcn_mfma_f32_16x16x32_bf16(a[mi], b1[ni], acc1[mi][ni], 0, 0, 0);
        }
    }
    __syncthreads();
  }

  short* comb = kh ? comb1 : comb0;
  const int lq = lane >> 4;
  #pragma unroll
  for (int mi = 0; mi < 4; mi++) {
    #pragma unroll
    for (int jj = 0; jj < 4; jj++) {
      int r = wr * 64 + mi * 16 + lq * 4 + jj;
      int gr = row0 + r;
      if (gr < rows) {
        size_t orow = (size_t)(seg + gr) * DD + n0;
        #pragma unroll
        for (int ni = 0; ni < 4; ni++) {
          int c = wc * 64 + ni * 16 + lr;
          comb[orow + c] = f2bf(acc0[mi][ni][jj]);
          comb[orow + 128 + c] = f2bf(acc1[mi][ni][jj]);
        }
      }
    }
  }
}

// ---------------- launcher ----------------
extern "C" void kernel_launch(void* const* d_in, const int* in_sizes, int n_in,
                              void* d_out, int out_size, void* d_ws, size_t ws_size,
                              hipStream_t stream) {
  const float* x   = (const float*)d_in[0];
  const float* gk  = (const float*)d_in[1];
  const float* wi0 = (const float*)d_in[2];
  const float* wi1 = (const float*)d_in[3];
  const float* wo  = (const float*)d_in[4];
  float* out = (float*)d_out;

  char* w = (char*)d_ws;
  int*   counts  = (int*)(w);
  int*   offsets = (int*)(w + 256);
  int*   tkidx   = (int*)(w + 1024);
  float* tkw     = (float*)(w + 1024 + 65536);
  int*   ltok    = (int*)(w + 1024 + 2*65536);
  float* lwt     = (float*)(w + 1024 + 3*65536);
  int*   slots   = (int*)(w + 1024 + 4*65536);
  short* xbf  = (short*)(w + 524288);
  short* hbuf = xbf + (size_t)TT * DD;                     // 2T x M bf16
  short* w0t  = hbuf + (size_t)2 * TT * MM;
  short* w1t  = w0t + (size_t)NE * DD * MM;
  short* wot  = w1t + (size_t)NE * DD * MM;
  short* comb0 = w0t;  // reuse w0t region (64 MB) after gemm1
  short* comb1 = w1t;  // reuse w1t region (64 MB) after gemm1

  hipMemsetAsync(counts, 0, 64, stream);

  gate_fused<<<TT + GCVT01, 256, 0, stream>>>(x, gk, counts, tkidx, tkw, xbf,
                                              wi0, wi1, w0t, w1t);
  scatter_kernel<<<NE, 256, 0, stream>>>(counts, offsets, tkidx, tkw, ltok, lwt, slots);

  gemm1_fused<<<G1GRID + GOGRID, 256, 0, stream>>>(xbf, w0t, w1t, offsets, ltok, lwt,
                                                   hbuf, wo, wot);
  gemm2_fast<<<dim3(G1TILES, 16), 256, 0, stream>>>(hbuf, wot, offsets, comb0, comb1);
  combine_kernel<<<TT, 256, 0, stream>>>(comb0, comb1, slots, out);
}

// Round 18
// 839.041 us; speedup vs baseline: 1.0073x; 1.0073x over previous
//
#include <hip/hip_runtime.h>
#include <hip/hip_bf16.h>
#include <stdint.h>

#define TT   8192   // B*S tokens
#define DD   2048
#define MM   2048
#define NE   8

typedef float f32x4 __attribute__((ext_vector_type(4)));
typedef short s16x8 __attribute__((ext_vector_type(8)));
typedef unsigned int u32;
typedef unsigned long long u64;

static __device__ __forceinline__ short f2bf(float f) {
  __hip_bfloat16 h = __float2bfloat16(f);
  short s;
  __builtin_memcpy(&s, &h, 2);
  return s;
}
static __device__ __forceinline__ float bf2f(short s) {
  u32 u = ((u32)(unsigned short)s) << 16;
  float f;
  __builtin_memcpy(&f, &u, 4);
  return f;
}

static __device__ __forceinline__ void gload_lds16(const short* g, short* lds) {
  __builtin_amdgcn_global_load_lds(
      (const __attribute__((address_space(1))) u32*)g,
      (__attribute__((address_space(3))) u32*)lds, 16, 0, 0);
}

// ================= FUSED: gate+xcvt (blocks 0..TT) + wi0/wi1 transpose (rest) =========
#define GCVT01  (16 * 32 * 32)     // 16384 transpose tiles (wi0, wi1)

__global__ __launch_bounds__(256) void gate_fused(
    const float* __restrict__ x, const float* __restrict__ gk,
    int* __restrict__ counts, int* __restrict__ tkidx, float* __restrict__ tkw,
    short* __restrict__ xbf,
    const float* __restrict__ wi0, const float* __restrict__ wi1,
    short* __restrict__ o0, short* __restrict__ o1) {
  __shared__ short tile[64][65];
  __shared__ float red[4][NE];

  const int bid = blockIdx.x;
  if (bid >= TT) {
    // ---- tcvt01 role: transpose-convert one 64x64 tile of wi0/wi1 ----
    const int idx = bid - TT;
    const int wz = idx >> 10;                // 0..15
    const float* in  = (wz < 8) ? wi0 : wi1;
    short* out       = (wz < 8) ? o0 : o1;
    const int ex = wz & 7;
    const int rem = idx & 1023;
    const int r0 = (rem >> 5) * 64;
    const int c0 = (rem & 31) * 64;
    const float* src = in + (size_t)ex * DD * MM;
    short* dst = out + (size_t)ex * DD * MM;
    const int t = threadIdx.x;
    const int rr = t >> 4, cc = (t & 15) * 4;
    #pragma unroll
    for (int i = 0; i < 4; i++) {
      int row = rr + i * 16;
      f32x4 v = *(const f32x4*)(src + (size_t)(r0 + row) * MM + c0 + cc);
      tile[cc + 0][row] = f2bf(v[0]);
      tile[cc + 1][row] = f2bf(v[1]);
      tile[cc + 2][row] = f2bf(v[2]);
      tile[cc + 3][row] = f2bf(v[3]);
    }
    __syncthreads();
    const int orow = t >> 2, c8 = (t & 3) * 16;
    s16x8 v0, v1;
    #pragma unroll
    for (int i = 0; i < 8; i++) { v0[i] = tile[orow][c8 + i]; v1[i] = tile[orow][c8 + 8 + i]; }
    short* dp = dst + (size_t)(c0 + orow) * DD + r0 + c8;
    *(s16x8*)(dp) = v0;
    *(s16x8*)(dp + 8) = v1;
    return;
  }

  // ---- gate role: fp32 logits, top-2, softmax; writes xbf ----
  const int t = bid;
  const float* xr = x + (size_t)t * DD;
  const int d0 = threadIdx.x * 8;
  f32x4 a = *(const f32x4*)(xr + d0);
  f32x4 b = *(const f32x4*)(xr + d0 + 4);
  s16x8 v;
  v[0]=f2bf(a[0]); v[1]=f2bf(a[1]); v[2]=f2bf(a[2]); v[3]=f2bf(a[3]);
  v[4]=f2bf(b[0]); v[5]=f2bf(b[1]); v[6]=f2bf(b[2]); v[7]=f2bf(b[3]);
  *(s16x8*)(xbf + (size_t)t * DD + d0) = v;

  float acc[NE];
  #pragma unroll
  for (int e = 0; e < NE; e++) acc[e] = 0.f;
  #pragma unroll
  for (int j = 0; j < 8; j++) {
    float xv = (j < 4) ? a[j] : b[j - 4];
    const float* g = gk + (size_t)(d0 + j) * NE;
    #pragma unroll
    for (int e = 0; e < NE; e++) acc[e] += xv * g[e];
  }
  #pragma unroll
  for (int e = 0; e < NE; e++) {
    #pragma unroll
    for (int off = 32; off >= 1; off >>= 1)
      acc[e] += __shfl_xor(acc[e], off, 64);
  }
  int wid = threadIdx.x >> 6;
  int lane = threadIdx.x & 63;
  if (lane == 0) {
    #pragma unroll
    for (int e = 0; e < NE; e++) red[wid][e] = acc[e];
  }
  __syncthreads();
  if (threadIdx.x == 0) {
    float l[NE];
    #pragma unroll
    for (int e = 0; e < NE; e++) l[e] = red[0][e] + red[1][e] + red[2][e] + red[3][e];
    int i1 = 0; float v1 = l[0];
    #pragma unroll
    for (int e = 1; e < NE; e++) if (l[e] > v1) { v1 = l[e]; i1 = e; }
    int i2 = -1; float v2 = -1e30f;
    #pragma unroll
    for (int e = 0; e < NE; e++) if (e != i1 && l[e] > v2) { v2 = l[e]; i2 = e; }
    float p = __expf(v2 - v1);
    float inv = 1.f / (1.f + p);
    tkidx[t*2]   = i1; tkidx[t*2+1] = i2;
    tkw[t*2]     = inv; tkw[t*2+1]  = p * inv;
    atomicAdd(&counts[i1], 1);
    atomicAdd(&counts[i2], 1);
  }
}

// ---------------- scatter: 8 blocks, deterministic ballot compaction (+ slot map) ------
__global__ __launch_bounds__(256) void scatter_kernel(const int* __restrict__ counts,
    int* __restrict__ offsets, const int* __restrict__ tkidx,
    const float* __restrict__ tkw, int* __restrict__ ltok, float* __restrict__ lwt,
    int* __restrict__ slots) {
  const int e = blockIdx.x;
  const int tid = threadIdx.x;
  const int wid = tid >> 6, lane = tid & 63;
  __shared__ int base_s;
  __shared__ int wsum[4];
  if (tid == 0) {
    int s = 0;
    #pragma unroll
    for (int i = 0; i < NE; i++) {
      if (e == 0) offsets[i] = s;
      if (i < e) s += counts[i];
      else if (e == 0) s += counts[i];
    }
    if (e == 0) offsets[NE] = s;
    int bs = 0;
    for (int i = 0; i < e; i++) bs += counts[i];
    base_s = bs;
  }
  __syncthreads();
  int base = base_s;
  for (int it = 0; it < (TT * 2) / 256; it++) {
    int i = it * 256 + tid;
    bool m = (tkidx[i] == e);
    u64 b = __ballot(m);
    if (lane == 0) wsum[wid] = __popcll(b);
    __syncthreads();
    int pre = 0;
    #pragma unroll
    for (int w = 0; w < 4; w++) if (w < wid) pre += wsum[w];
    int tot = wsum[0] + wsum[1] + wsum[2] + wsum[3];
    int rank = __popcll(b & ((lane == 0) ? 0ull : ((1ull << lane) - 1ull)));
    if (m) {
      int dst = base + pre + rank;
      ltok[dst] = i >> 1;
      lwt[dst]  = tkw[i];
      slots[i]  = dst;
    }
    __syncthreads();
    base += tot;
  }
}

// ---------------- combine: out[t] = comb[slot0] + comb[slot1] (bf16 comb) ----------------
__global__ __launch_bounds__(256) void combine_kernel(const short* __restrict__ comb,
    const int* __restrict__ slots, float* __restrict__ out) {
  const int t = blockIdx.x;
  const int s0 = slots[2 * t], s1 = slots[2 * t + 1];
  const int idx = threadIdx.x;
  s16x8 a = *(const s16x8*)(comb + (size_t)s0 * DD + idx * 8);
  s16x8 b = *(const s16x8*)(comb + (size_t)s1 * DD + idx * 8);
  f32x4 o0, o1;
  #pragma unroll
  for (int j = 0; j < 4; j++) {
    o0[j] = bf2f(a[j]) + bf2f(b[j]);
    o1[j] = bf2f(a[4 + j]) + bf2f(b[4 + j]);
  }
  float* po = out + (size_t)t * DD + idx * 8;
  *(f32x4*)(po) = o0;
  *(f32x4*)(po + 4) = o1;
}

// ---------------- segment lookup ----------------
__device__ __forceinline__ void find_seg(const int* __restrict__ offsets, int tile, int bm,
                                         int& e, int& row0, int& rows, int& seg) {
  e = -1; row0 = 0; rows = 0; seg = 0;
  int accT = 0, prev = offsets[0];
  #pragma unroll
  for (int i = 0; i < NE; i++) {
    int nxt = offsets[i+1];
    int cnt = nxt - prev;
    int nt = (cnt + bm - 1) / bm;
    if (e < 0 && tile < accT + nt) { e = i; row0 = (tile - accT) * bm; rows = cnt; seg = prev; }
    accT += nt; prev = nxt;
  }
}

// XCD-chunked swizzle (bijective: nwg % 8 == 0); y varies fastest within an XCD chunk.
__device__ __forceinline__ void xcd_map(int ypx, int& tile, int& nyi) {
  const int bid = blockIdx.y * gridDim.x + blockIdx.x;
  const int xcd = bid & 7;
  const int i = bid >> 3;
  tile = i / ypx;
  nyi  = xcd * ypx + (i % ypx);
}

// ================= FUSED: gemm1 (blocks 0..G1GRID) + wo-transpose (rest) =================
#define G1TILES 136
#define G1GRID  (G1TILES * 16)     // 2176, %8==0 (bijective swizzle)
#define GOGRID  (8 * 32 * 32)      // 8192 transpose tiles

__global__ __launch_bounds__(256, 2) void gemm1_fused(
    const short* __restrict__ xbf,
    const short* __restrict__ w0t, const short* __restrict__ w1t,
    const int* __restrict__ offsets,
    const int* __restrict__ ltok, const float* __restrict__ lwt,
    short* __restrict__ hbuf,
    const float* __restrict__ wo, short* __restrict__ wot) {
  __shared__ short As[128 * 64];
  __shared__ short B0s[128 * 64];
  __shared__ short B1s[128 * 64];
  __shared__ float w_s[128];

  const int bid = blockIdx.x;
  if (bid >= G1GRID) {
    short (*tile)[65] = (short(*)[65])As;
    const int idx = bid - G1GRID;
    const int ex = idx >> 10;
    const int rem = idx & 1023;
    const int r0 = (rem >> 5) * 64;
    const int c0 = (rem & 31) * 64;
    const float* src = wo + (size_t)ex * DD * MM;
    short* dst = wot + (size_t)ex * DD * MM;
    const int t = threadIdx.x;
    const int rr = t >> 4, cc = (t & 15) * 4;
    #pragma unroll
    for (int i = 0; i < 4; i++) {
      int row = rr + i * 16;
      f32x4 v = *(const f32x4*)(src + (size_t)(r0 + row) * MM + c0 + cc);
      tile[cc + 0][row] = f2bf(v[0]);
      tile[cc + 1][row] = f2bf(v[1]);
      tile[cc + 2][row] = f2bf(v[2]);
      tile[cc + 3][row] = f2bf(v[3]);
    }
    __syncthreads();
    const int orow = t >> 2, c8 = (t & 3) * 16;
    s16x8 v0, v1;
    #pragma unroll
    for (int i = 0; i < 8; i++) { v0[i] = tile[orow][c8 + i]; v1[i] = tile[orow][c8 + 8 + i]; }
    short* dp = dst + (size_t)(c0 + orow) * DD + r0 + c8;
    *(s16x8*)(dp) = v0;
    *(s16x8*)(dp + 8) = v1;
    return;
  }

  const int xcd = bid & 7;
  const int bi = bid >> 3;
  const int tile = bi >> 1;
  const int nyi = xcd * 2 + (bi & 1);
  const int n0 = nyi * 128;
  int e, row0, rows, seg;
  find_seg(offsets, tile, 128, e, row0, rows, seg);
  if (e < 0) return;

  const int tid = threadIdx.x;
  const int lane = tid & 63, wid = tid >> 6;
  if (tid < 128) {
    int gr = row0 + tid;
    w_s[tid] = (gr < rows) ? lwt[seg + gr] : 0.f;
  }

  const int swz = ((lane & 7) ^ (lane >> 3)) * 8;
  const short* abase[4];
  const short* b0base[4];
  const short* b1base[4];
  #pragma unroll
  for (int c = 0; c < 4; c++) {
    int chunk = wid * 4 + c;
    int r = chunk * 8 + (lane >> 3);
    int gr = row0 + r; if (gr >= rows) gr = rows - 1;
    int tok = ltok[seg + gr];
    abase[c]  = xbf + (size_t)tok * DD + swz;
    int n = n0 + r;
    b0base[c] = w0t + ((size_t)e * MM + n) * DD + swz;
    b1base[c] = w1t + ((size_t)e * MM + n) * DD + swz;
  }

  const int wr = wid >> 1, wc = wid & 1;
  const int lr = lane & 15;
  const int kq = (lane >> 4) * 8;

  f32x4 acc0[4][4], acc1[4][4];
  #pragma unroll
  for (int i = 0; i < 4; i++)
    #pragma unroll
    for (int j = 0; j < 4; j++) { acc0[i][j] = 0.f; acc1[i][j] = 0.f; }

  for (int k0 = 0; k0 < DD; k0 += 64) {
    #pragma unroll
    for (int c = 0; c < 4; c++) {
      int chunk = wid * 4 + c;
      gload_lds16(abase[c]  + k0, As  + chunk * 512);
      gload_lds16(b0base[c] + k0, B0s + chunk * 512);
      gload_lds16(b1base[c] + k0, B1s + chunk * 512);
    }
    __syncthreads();

    #pragma unroll
    for (int ks = 0; ks < 2; ks++) {
      s16x8 a[4], b0[4], b1[4];
      #pragma unroll
      for (int mi = 0; mi < 4; mi++) {
        int row = wr * 64 + mi * 16 + lr;
        int koff = (ks * 32 + kq) ^ ((row & 7) * 8);
        a[mi] = *(const s16x8*)&As[row * 64 + koff];
      }
      #pragma unroll
      for (int ni = 0; ni < 4; ni++) {
        int row = wc * 64 + ni * 16 + lr;
        int koff = (ks * 32 + kq) ^ ((row & 7) * 8);
        b0[ni] = *(const s16x8*)&B0s[row * 64 + koff];
        b1[ni] = *(const s16x8*)&B1s[row * 64 + koff];
      }
      #pragma unroll
      for (int mi = 0; mi < 4; mi++)
        #pragma unroll
        for (int ni = 0; ni < 4; ni++) {
          acc0[mi][ni] = __builtin_amdgcn_mfma_f32_16x16x32_bf16(a[mi], b0[ni], acc0[mi][ni], 0, 0, 0);
          acc1[mi][ni] = __builtin_amdgcn_mfma_f32_16x16x32_bf16(a[mi], b1[ni], acc1[mi][ni], 0, 0, 0);
        }
    }
    __syncthreads();
  }

  const int lq = lane >> 4;
  #pragma unroll
  for (int mi = 0; mi < 4; mi++) {
    #pragma unroll
    for (int jj = 0; jj < 4; jj++) {
      int r = wr * 64 + mi * 16 + lq * 4 + jj;
      int gr = row0 + r;
      if (gr < rows) {
        float wgt = w_s[r];
        size_t hrow = (size_t)(seg + gr) * MM + n0;
        #pragma unroll
        for (int ni = 0; ni < 4; ni++) {
          int c = wc * 64 + ni * 16 + lr;
          float g = acc0[mi][ni][jj];
          float u = acc1[mi][ni][jj];
          float act = g / (1.f + __expf(-g));
          hbuf[hrow + c] = f2bf(act * u * wgt);
        }
      }
    }
  }
}

// ================= GEMM2: simple 2-barrier, BM=128 rows x dual 128-col B (BN=256) ======
// Same template as gemm1 (48 KB LDS, 2 blocks/CU), bf16 comb epilogue.
__global__ __launch_bounds__(256, 2) void gemm2_fast(
    const short* __restrict__ hbuf,
    const short* __restrict__ wot,
    const int* __restrict__ offsets,
    short* __restrict__ comb) {
  __shared__ short As[128 * 64];
  __shared__ short B0s[128 * 64];
  __shared__ short B1s[128 * 64];

  int tile, nyi;
  xcd_map(1, tile, nyi);             // grid (136, 8): 1088 blocks, 1 y-slice per XCD
  const int n0 = nyi * 256;
  int e, row0, rows, seg;
  find_seg(offsets, tile, 128, e, row0, rows, seg);
  if (e < 0) return;

  const int tid = threadIdx.x;
  const int lane = tid & 63, wid = tid >> 6;

  const int swz = ((lane & 7) ^ (lane >> 3)) * 8;
  const short* abase[4];
  const short* b0base[4];
  const short* b1base[4];
  #pragma unroll
  for (int c = 0; c < 4; c++) {
    int chunk = wid * 4 + c;
    int r = chunk * 8 + (lane >> 3);
    int gr = row0 + r; if (gr >= rows) gr = rows - 1;
    abase[c] = hbuf + (size_t)(seg + gr) * MM + swz;
    b0base[c] = wot + ((size_t)e * DD + n0 + r) * MM + swz;
    b1base[c] = wot + ((size_t)e * DD + n0 + 128 + r) * MM + swz;
  }

  const int wr = wid >> 1, wc = wid & 1;
  const int lr = lane & 15;
  const int kq = (lane >> 4) * 8;

  f32x4 acc0[4][4], acc1[4][4];
  #pragma unroll
  for (int i = 0; i < 4; i++)
    #pragma unroll
    for (int j = 0; j < 4; j++) { acc0[i][j] = 0.f; acc1[i][j] = 0.f; }

  for (int k0 = 0; k0 < MM; k0 += 64) {
    #pragma unroll
    for (int c = 0; c < 4; c++) {
      int chunk = wid * 4 + c;
      gload_lds16(abase[c]  + k0, As  + chunk * 512);
      gload_lds16(b0base[c] + k0, B0s + chunk * 512);
      gload_lds16(b1base[c] + k0, B1s + chunk * 512);
    }
    __syncthreads();

    #pragma unroll
    for (int ks = 0; ks < 2; ks++) {
      s16x8 a[4], b0[4], b1[4];
      #pragma unroll
      for (int mi = 0; mi < 4; mi++) {
        int row = wr * 64 + mi * 16 + lr;
        int koff = (ks * 32 + kq) ^ ((row & 7) * 8);
        a[mi] = *(const s16x8*)&As[row * 64 + koff];
      }
      #pragma unroll
      for (int ni = 0; ni < 4; ni++) {
        int row = wc * 64 + ni * 16 + lr;
        int koff = (ks * 32 + kq) ^ ((row & 7) * 8);
        b0[ni] = *(const s16x8*)&B0s[row * 64 + koff];
        b1[ni] = *(const s16x8*)&B1s[row * 64 + koff];
      }
      #pragma unroll
      for (int mi = 0; mi < 4; mi++)
        #pragma unroll
        for (int ni = 0; ni < 4; ni++) {
          acc0[mi][ni] = __builtin_amdgcn_mfma_f32_16x16x32_bf16(a[mi], b0[ni], acc0[mi][ni], 0, 0, 0);
          acc1[mi][ni] = __builtin_amdgcn_mfma_f32_16x16x32_bf16(a[mi], b1[ni], acc1[mi][ni], 0, 0, 0);
        }
    }
    __syncthreads();
  }

  const int lq = lane >> 4;
  #pragma unroll
  for (int mi = 0; mi < 4; mi++) {
    #pragma unroll
    for (int jj = 0; jj < 4; jj++) {
      int r = wr * 64 + mi * 16 + lq * 4 + jj;
      int gr = row0 + r;
      if (gr < rows) {
        size_t orow = (size_t)(seg + gr) * DD + n0;
        #pragma unroll
        for (int ni = 0; ni < 4; ni++) {
          int c = wc * 64 + ni * 16 + lr;
          comb[orow + c] = f2bf(acc0[mi][ni][jj]);
          comb[orow + 128 + c] = f2bf(acc1[mi][ni][jj]);
        }
      }
    }
  }
}

// ---------------- launcher ----------------
extern "C" void kernel_launch(void* const* d_in, const int* in_sizes, int n_in,
                              void* d_out, int out_size, void* d_ws, size_t ws_size,
                              hipStream_t stream) {
  const float* x   = (const float*)d_in[0];
  const float* gk  = (const float*)d_in[1];
  const float* wi0 = (const float*)d_in[2];
  const float* wi1 = (const float*)d_in[3];
  const float* wo  = (const float*)d_in[4];
  float* out = (float*)d_out;

  char* w = (char*)d_ws;
  int*   counts  = (int*)(w);
  int*   offsets = (int*)(w + 256);
  int*   tkidx   = (int*)(w + 1024);
  float* tkw     = (float*)(w + 1024 + 65536);
  int*   ltok    = (int*)(w + 1024 + 2*65536);
  float* lwt     = (float*)(w + 1024 + 3*65536);
  int*   slots   = (int*)(w + 1024 + 4*65536);
  short* xbf  = (short*)(w + 524288);
  short* hbuf = xbf + (size_t)TT * DD;                     // 2T x M bf16
  short* w0t  = hbuf + (size_t)2 * TT * MM;
  short* w1t  = w0t + (size_t)NE * DD * MM;
  short* wot  = w1t + (size_t)NE * DD * MM;
  short* comb = w0t;   // reuse w0t region (bf16, 64 MB) after gemm1

  hipMemsetAsync(counts, 0, 64, stream);

  gate_fused<<<TT + GCVT01, 256, 0, stream>>>(x, gk, counts, tkidx, tkw, xbf,
                                              wi0, wi1, w0t, w1t);
  scatter_kernel<<<NE, 256, 0, stream>>>(counts, offsets, tkidx, tkw, ltok, lwt, slots);

  gemm1_fused<<<G1GRID + GOGRID, 256, 0, stream>>>(xbf, w0t, w1t, offsets, ltok, lwt,
                                                   hbuf, wo, wot);
  gemm2_fast<<<dim3(G1TILES, DD/256), 256, 0, stream>>>(hbuf, wot, offsets, comb);
  combine_kernel<<<TT, 256, 0, stream>>>(comb, slots, out);
}